// Round 2
// baseline (472.631 us; speedup 1.0000x reference)
//
#include <hip/hip_runtime.h>
#include <math.h>
#include <stdint.h>

// ---------------------------------------------------------------------------
// RadarPillarFeatureNet: N=200000 pillars x M=32 points x C=9 raw channels.
// Float tensor dtype (fp32 vs bf16) is detected at runtime from the bit
// pattern of `features` (k_detect); all compute kernels are instantiated for
// both dtypes and early-exit on a ws flag (uniform branch, graph-safe).
// Pipeline:
//   k_detect   : vote on exponent sanity of even u16 halves -> flag in ws
//   k_moments  : 68 global moments of the 16-ch derived feature
//   k_reduce   : column-reduce per-block partials -> 68 totals
//   k_finalize : per-unit mean/var -> S,T affine; pack MFMA B frags (hi+lo)
//   k_main     : derive -> LDS tile -> mfma_32x32x16_bf16 (split hi/lo in
//                fp32 mode for ~1e-5 rel accuracy) -> affine+relu+max -> out
// ---------------------------------------------------------------------------

typedef unsigned short u16_t;
typedef __bf16 bf16x8 __attribute__((ext_vector_type(8)));
typedef float floatx16 __attribute__((ext_vector_type(16)));

#define N_P     200000
#define NCHUNK  25000          // N_P / 8 pillars-per-block
#define CNT_TOT 6400000.0      // N*M

__device__ __forceinline__ float bf2f(u16_t u) {
  return __builtin_bit_cast(float, ((unsigned)u) << 16);
}
__device__ __forceinline__ u16_t f2bf(float f) {  // RNE
  unsigned u = __builtin_bit_cast(unsigned, f);
  u += 0x7FFFu + ((u >> 16) & 1u);
  return (u16_t)(u >> 16);
}

template<bool BF16>
__device__ __forceinline__ float ldval(const void* p, size_t i) {
  if constexpr (BF16) return bf2f(((const u16_t*)p)[i]);
  else                return ((const float*)p)[i];
}

// 52 within-branch second-moment pairs: b0(8ch)=36, b1(2)=3, b2(2)=3, b3(4)=10
struct Pairs { int pi[52]; int pj[52]; int pa[52]; int pb[52]; };
constexpr Pairs makePairs() {
  Pairs P{};
  int n = 0;
  const int L0[8] = {0, 1, 2, 5, 6, 7, 8, 9};
  for (int a = 0; a < 8; ++a)
    for (int b = a; b < 8; ++b) { P.pi[n]=L0[a]; P.pj[n]=L0[b]; P.pa[n]=a; P.pb[n]=b; ++n; }
  const int L1[2] = {3, 10};
  for (int a = 0; a < 2; ++a)
    for (int b = a; b < 2; ++b) { P.pi[n]=L1[a]; P.pj[n]=L1[b]; P.pa[n]=a; P.pb[n]=b; ++n; }
  const int L2[2] = {4, 11};
  for (int a = 0; a < 2; ++a)
    for (int b = a; b < 2; ++b) { P.pi[n]=L2[a]; P.pj[n]=L2[b]; P.pa[n]=a; P.pb[n]=b; ++n; }
  const int L3[4] = {12, 13, 14, 15};
  for (int a = 0; a < 4; ++a)
    for (int b = a; b < 4; ++b) { P.pi[n]=L3[a]; P.pj[n]=L3[b]; P.pa[n]=a; P.pb[n]=b; ++n; }
  return P;
}
constexpr Pairs PT = makePairs();

// ---------------- dtype detection ------------------------------------------
// fp32 data read at even u16 indices = low mantissa halves -> random exponent
// (~16% "sane"); bf16 data -> ~100% sane. 256-sample vote.
__global__ void k_detect(const u16_t* __restrict__ f, int* __restrict__ flag) {
  int tid = threadIdx.x;  // 64
  int cnt = 0;
  for (int i = 0; i < 4; ++i) {
    unsigned v = f[(size_t)(tid * 4 + i) * 2];
    unsigned e = (v >> 7) & 0xFF;
    cnt += (e >= 100 && e <= 140) ? 1 : 0;
  }
  for (int s = 1; s < 64; s <<= 1) cnt += __shfl_xor(cnt, s);
  if (tid == 0) *flag = (cnt >= 160) ? 1 : 0;   // 1 == bf16
}

// Derived 16-channel feature for (pillar p, point m). Per-pillar sums over all
// 32 raw points (reference sums unmasked raws) via 32-lane shfl butterflies.
template<bool BF16>
__device__ __forceinline__ void derive_feat(
    const void* __restrict__ feats, const int* __restrict__ nump,
    const int* __restrict__ coors, int p, int m, float* feat) {
  size_t base = ((size_t)p * 32 + m) * 9;
  float r[9];
#pragma unroll
  for (int c = 0; c < 9; ++c) r[c] = ldval<BF16>(feats, base + c);
  float sx = r[0], sy = r[1], sz = r[2], svx = r[3], svy = r[4];
#pragma unroll
  for (int sft = 1; sft < 32; sft <<= 1) {   // masks <32 stay within 32-lane group
    sx  += __shfl_xor(sx,  sft);
    sy  += __shfl_xor(sy,  sft);
    sz  += __shfl_xor(sz,  sft);
    svx += __shfl_xor(svx, sft);
    svy += __shfl_xor(svy, sft);
  }
  int np = nump[p];
  float inv = 1.0f / (float)np;
  float cx = (float)coors[p * 4 + 3] * 0.2f + 0.1f;
  float cy = (float)coors[p * 4 + 2] * 0.2f - 39.9f;
  feat[0] = r[0] - cx;
  feat[1] = r[1] - cy;
  feat[2] = r[2]; feat[3] = r[3]; feat[4] = r[4];
  feat[5] = r[5]; feat[6] = r[6]; feat[7] = r[7]; feat[8] = r[8];
  feat[9]  = r[0] - sx * inv;
  feat[10] = r[1] - sy * inv;
  feat[11] = r[2] - sz * inv;
  feat[12] = feat[0];
  feat[13] = feat[1];
  feat[14] = r[3] - svx * inv;
  feat[15] = r[4] - svy * inv;
  if (m >= np) {
#pragma unroll
    for (int c = 0; c < 16; ++c) feat[c] = 0.0f;
  }
}

// ---------------- Pass 1: 68 moments ---------------------------------------
template<bool BF16>
__global__ void k_moments(const void* __restrict__ feats,
                          const int* __restrict__ nump,
                          const int* __restrict__ coors,
                          const int* __restrict__ flag,
                          float* __restrict__ part, int g1) {
  if (*flag != (BF16 ? 1 : 0)) return;
  int tid = threadIdx.x;
  int wave = tid >> 6, lane = tid & 63;
  int pp = (lane >> 5) & 1, m = lane & 31;
  float acc[68];
#pragma unroll
  for (int i = 0; i < 68; ++i) acc[i] = 0.0f;

  for (int chunk = blockIdx.x; chunk < NCHUNK; chunk += g1) {
    int p = chunk * 8 + wave * 2 + pp;
    float feat[16];
    derive_feat<BF16>(feats, nump, coors, p, m, feat);
#pragma unroll
    for (int c = 0; c < 16; ++c) acc[c] += feat[c];
#pragma unroll
    for (int t = 0; t < 52; ++t)
      acc[16 + t] = fmaf(feat[PT.pi[t]], feat[PT.pj[t]], acc[16 + t]);
  }

#pragma unroll
  for (int k = 0; k < 68; ++k) {
    float v = acc[k];
#pragma unroll
    for (int sft = 1; sft < 64; sft <<= 1) v += __shfl_xor(v, sft);
    acc[k] = v;
  }
  __shared__ float red[4][68];
  if (lane == 0) {
#pragma unroll
    for (int k = 0; k < 68; ++k) red[wave][k] = acc[k];
  }
  __syncthreads();
  if (tid < 68) {
    float t = red[0][tid] + red[1][tid] + red[2][tid] + red[3][tid];
    part[(size_t)tid * g1 + blockIdx.x] = t;
  }
}

// ---------------- Pass 1b --------------------------------------------------
__global__ void k_reduce(const float* __restrict__ part,
                         float* __restrict__ mom, int g1) {
  int j = blockIdx.x, tid = threadIdx.x;
  float s = 0.0f;
  for (int b = tid; b < g1; b += 256) s += part[(size_t)j * g1 + b];
  __shared__ float red[256];
  red[tid] = s;
  __syncthreads();
  for (int off = 128; off; off >>= 1) {
    if (tid < off) red[tid] += red[tid + off];
    __syncthreads();
  }
  if (tid == 0) mom[j] = red[0];
}

// ---------------- Finalize -------------------------------------------------
template<bool BF16>
__device__ __forceinline__ float wval(int u, int c,
    const void* w1, const void* w2, const void* w3, const void* w4) {
  int b = u >> 4, k = u & 15;
  if (b == 0) {
    int k2 = (c <= 2) ? c : ((c >= 5 && c <= 9) ? c - 2 : -1);
    return (k2 >= 0) ? ldval<BF16>(w1, k * 8 + k2) : 0.0f;
  } else if (b == 1) {
    if (c == 3)  return ldval<BF16>(w2, k * 2 + 0);
    if (c == 10) return ldval<BF16>(w2, k * 2 + 1);
    return 0.0f;
  } else if (b == 2) {
    if (c == 4)  return ldval<BF16>(w3, k * 2 + 0);
    if (c == 11) return ldval<BF16>(w3, k * 2 + 1);
    return 0.0f;
  }
  if (c >= 12) return ldval<BF16>(w4, k * 4 + (c - 12));
  return 0.0f;
}

template<bool BF16>
__global__ void k_finalize(const float* __restrict__ mom,
    const void* __restrict__ w1, const void* __restrict__ w2,
    const void* __restrict__ w3, const void* __restrict__ w4,
    const void* __restrict__ gamma, const void* __restrict__ beta,
    const int* __restrict__ flag,
    float* __restrict__ wsS, float* __restrict__ wsT,
    uint4* __restrict__ wsB0hi, uint4* __restrict__ wsB0lo,
    uint4* __restrict__ wsB1hi, uint4* __restrict__ wsB1lo) {
  if (*flag != (BF16 ? 1 : 0)) return;
  int u = threadIdx.x;  // 0..63 == branch*16 + unit-in-branch
  const int CHOFF[4] = {0, 8, 10, 12};
  const int CCNT[4]  = {8, 2, 2, 4};
  const int LCH[16]  = {0,1,2,5,6,7,8,9, 3,10, 4,11, 12,13,14,15};
  const int PBASE[4] = {0, 36, 39, 42};
  const int PCNTB[4] = {36, 3, 3, 10};

  int b = u >> 4, k = u & 15;
  const void* wsrc = (b == 0) ? w1 : (b == 1) ? w2 : (b == 2) ? w3 : w4;
  int cc = CCNT[b];
  float  w[8];
  double mf[8];
  for (int i = 0; i < 8; ++i) { w[i] = 0.0f; mf[i] = 0.0; }
  for (int i = 0; i < cc; ++i) {
    w[i]  = ldval<BF16>(wsrc, k * cc + i);
    mf[i] = (double)mom[LCH[CHOFF[b] + i]] / CNT_TOT;
  }
  double mu = 0.0;
  for (int i = 0; i < cc; ++i) mu += (double)w[i] * mf[i];
  double var = 0.0;
  for (int t = 0; t < PCNTB[b]; ++t) {
    int idx = PBASE[b] + t;
    int a = PT.pa[idx], b2 = PT.pb[idx];
    double e2  = (double)mom[16 + idx] / CNT_TOT;
    double cov = e2 - mf[a] * mf[b2];
    var += ((a == b2) ? 1.0 : 2.0) * (double)w[a] * (double)w[b2] * cov;
  }
  float g  = ldval<BF16>(gamma, u);   // gamma/beta flat (4,16) == index u
  float be = ldval<BF16>(beta, u);
  float S = (float)(1.0 / sqrt(var + 1e-3)) * g;
  float T = be - (float)mu * S;
  wsS[u] = S;
  wsT[u] = T;

  // B frags for v_mfma_f32_32x32x16_bf16: lane l holds B[k=(l>>5)*8+j][n=l&31]
  int n = u & 31;
  u16_t h0[8], l0[8], h1[8], l1[8];
#pragma unroll
  for (int j = 0; j < 8; ++j) {
    int c = ((u >> 5) << 3) + j;
    float v0 = wval<BF16>(n,      c, w1, w2, w3, w4);
    float v1 = wval<BF16>(n + 32, c, w1, w2, w3, w4);
    h0[j] = f2bf(v0); h1[j] = f2bf(v1);
    l0[j] = BF16 ? (u16_t)0 : f2bf(v0 - bf2f(h0[j]));
    l1[j] = BF16 ? (u16_t)0 : f2bf(v1 - bf2f(h1[j]));
  }
  uint4 a0, a1, c0, c1;
  a0.x = h0[0] | ((unsigned)h0[1] << 16); a0.y = h0[2] | ((unsigned)h0[3] << 16);
  a0.z = h0[4] | ((unsigned)h0[5] << 16); a0.w = h0[6] | ((unsigned)h0[7] << 16);
  c0.x = l0[0] | ((unsigned)l0[1] << 16); c0.y = l0[2] | ((unsigned)l0[3] << 16);
  c0.z = l0[4] | ((unsigned)l0[5] << 16); c0.w = l0[6] | ((unsigned)l0[7] << 16);
  a1.x = h1[0] | ((unsigned)h1[1] << 16); a1.y = h1[2] | ((unsigned)h1[3] << 16);
  a1.z = h1[4] | ((unsigned)h1[5] << 16); a1.w = h1[6] | ((unsigned)h1[7] << 16);
  c1.x = l1[0] | ((unsigned)l1[1] << 16); c1.y = l1[2] | ((unsigned)l1[3] << 16);
  c1.z = l1[4] | ((unsigned)l1[5] << 16); c1.w = l1[6] | ((unsigned)l1[7] << 16);
  wsB0hi[u] = a0; wsB0lo[u] = c0;
  wsB1hi[u] = a1; wsB1lo[u] = c1;
}

// ---------------- Pass 2 ---------------------------------------------------
template<bool BF16>
__global__ __launch_bounds__(256) void k_main(
    const void* __restrict__ feats, const int* __restrict__ nump,
    const int* __restrict__ coors, const int* __restrict__ flag,
    const float* __restrict__ wsS, const float* __restrict__ wsT,
    const uint4* __restrict__ wsB0hi, const uint4* __restrict__ wsB0lo,
    const uint4* __restrict__ wsB1hi, const uint4* __restrict__ wsB1lo,
    void* __restrict__ outv) {
  if (*flag != (BF16 ? 1 : 0)) return;
  // hi tile (+ lo tile in fp32 mode); row stride 3*uint4 to spread banks
  constexpr int TILE = 8 * 32 * 3;
  __shared__ uint4 featL[(BF16 ? 1 : 2) * TILE];
  int tid = threadIdx.x;
  int wave = tid >> 6, lane = tid & 63;
  int pp = (lane >> 5) & 1, m = lane & 31;

  bf16x8 B0h = __builtin_bit_cast(bf16x8, wsB0hi[lane]);
  bf16x8 B1h = __builtin_bit_cast(bf16x8, wsB1hi[lane]);
  bf16x8 B0l, B1l;
  if constexpr (!BF16) {
    B0l = __builtin_bit_cast(bf16x8, wsB0lo[lane]);
    B1l = __builtin_bit_cast(bf16x8, wsB1lo[lane]);
  }
  int ucol = lane & 31;
  float s0 = wsS[ucol],      t0 = wsT[ucol];
  float s1 = wsS[ucol + 32], t1 = wsT[ucol + 32];

  int wp = wave * 2 + pp;
  int p  = blockIdx.x * 8 + wp;
  float feat[16];
  derive_feat<BF16>(feats, nump, coors, p, m, feat);

  unsigned pkh[8], pkl[8];
#pragma unroll
  for (int j = 0; j < 8; ++j) {
    float a0 = feat[2 * j], a1 = feat[2 * j + 1];
    u16_t h0 = f2bf(a0), h1 = f2bf(a1);
    pkh[j] = (unsigned)h0 | ((unsigned)h1 << 16);
    if constexpr (!BF16) {
      u16_t q0 = f2bf(a0 - bf2f(h0)), q1 = f2bf(a1 - bf2f(h1));
      pkl[j] = (unsigned)q0 | ((unsigned)q1 << 16);
    }
  }
  uint4 v;
  v.x = pkh[0]; v.y = pkh[1]; v.z = pkh[2]; v.w = pkh[3];
  featL[(wp * 32 + m) * 3 + 0] = v;
  v.x = pkh[4]; v.y = pkh[5]; v.z = pkh[6]; v.w = pkh[7];
  featL[(wp * 32 + m) * 3 + 1] = v;
  if constexpr (!BF16) {
    v.x = pkl[0]; v.y = pkl[1]; v.z = pkl[2]; v.w = pkl[3];
    featL[TILE + (wp * 32 + m) * 3 + 0] = v;
    v.x = pkl[4]; v.y = pkl[5]; v.z = pkl[6]; v.w = pkl[7];
    featL[TILE + (wp * 32 + m) * 3 + 1] = v;
  }
  __syncthreads();

  floatx16 z;
#pragma unroll
  for (int i = 0; i < 16; ++i) z[i] = 0.0f;

#pragma unroll
  for (int q = 0; q < 2; ++q) {
    int wq = wave * 2 + q;
    // A frag: lane l holds A[row=l&31][k=(l>>5)*8+j]; same k rule as B packing
    int ridx = (wq * 32 + (lane & 31)) * 3 + (lane >> 5);
    bf16x8 Ah = __builtin_bit_cast(bf16x8, featL[ridx]);
    floatx16 d0, d1;
    if constexpr (BF16) {
      d0 = __builtin_amdgcn_mfma_f32_32x32x16_bf16(Ah, B0h, z, 0, 0, 0);
      d1 = __builtin_amdgcn_mfma_f32_32x32x16_bf16(Ah, B1h, z, 0, 0, 0);
    } else {
      bf16x8 Al = __builtin_bit_cast(bf16x8, featL[TILE + ridx]);
      d0 = __builtin_amdgcn_mfma_f32_32x32x16_bf16(Al, B0h, z, 0, 0, 0);
      d0 = __builtin_amdgcn_mfma_f32_32x32x16_bf16(Ah, B0l, d0, 0, 0, 0);
      d0 = __builtin_amdgcn_mfma_f32_32x32x16_bf16(Ah, B0h, d0, 0, 0, 0);
      d1 = __builtin_amdgcn_mfma_f32_32x32x16_bf16(Al, B1h, z, 0, 0, 0);
      d1 = __builtin_amdgcn_mfma_f32_32x32x16_bf16(Ah, B1l, d1, 0, 0, 0);
      d1 = __builtin_amdgcn_mfma_f32_32x32x16_bf16(Ah, B1h, d1, 0, 0, 0);
    }
    // D layout: col=lane&31 (unit); 16 regs x 2 lane-halves tile the 32 rows
    // (row order irrelevant: max over rows)
    float mx0 = fmaf(d0[0], s0, t0);
    float mx1 = fmaf(d1[0], s1, t1);
#pragma unroll
    for (int r = 1; r < 16; ++r) {
      mx0 = fmaxf(mx0, fmaf(d0[r], s0, t0));
      mx1 = fmaxf(mx1, fmaf(d1[r], s1, t1));
    }
    mx0 = fmaxf(mx0, __shfl_xor(mx0, 32));
    mx1 = fmaxf(mx1, __shfl_xor(mx1, 32));
    mx0 = fmaxf(mx0, 0.0f);  // relu commutes with max
    mx1 = fmaxf(mx1, 0.0f);
    float val = (lane < 32) ? mx0 : mx1;  // out unit index == lane
    size_t oidx = (size_t)(blockIdx.x * 8 + wq) * 64 + lane;
    if constexpr (BF16) ((u16_t*)outv)[oidx] = f2bf(val);
    else                ((float*)outv)[oidx] = val;
  }
}

// ---------------------------------------------------------------------------
extern "C" void kernel_launch(void* const* d_in, const int* in_sizes, int n_in,
                              void* d_out, int out_size, void* d_ws, size_t ws_size,
                              hipStream_t stream) {
  (void)in_sizes; (void)n_in; (void)out_size;
  const void* feats = d_in[0];
  const void* w1    = d_in[1];
  const void* w2    = d_in[2];
  const void* w3    = d_in[3];
  const void* w4    = d_in[4];
  const void* gamma = d_in[5];
  const void* beta  = d_in[6];
  const int*  nump  = (const int*)d_in[7];
  const int*  coors = (const int*)d_in[8];

  char* ws = (char*)d_ws;
  int*   flag   = (int*)(ws + 0);
  float* wsS    = (float*)(ws + 64);      // 64 f32
  float* wsT    = (float*)(ws + 320);     // 64 f32
  uint4* wsB0hi = (uint4*)(ws + 576);     // 64 x 16B
  uint4* wsB0lo = (uint4*)(ws + 1600);
  uint4* wsB1hi = (uint4*)(ws + 2624);
  uint4* wsB1lo = (uint4*)(ws + 3648);
  float* mom    = (float*)(ws + 4672);    // 68 f32
  float* part   = (float*)(ws + 5120);    // 68 x g1 f32

  int g1 = 1024;
  size_t need = 5120 + (size_t)68 * (size_t)g1 * 4;
  if (need > ws_size) {
    size_t avail = (ws_size > 5120) ? (ws_size - 5120) : 0;
    g1 = (int)(avail / (68 * 4));
    if (g1 > 1024) g1 = 1024;
    if (g1 < 8) g1 = 8;
  }

  k_detect<<<1, 64, 0, stream>>>((const u16_t*)feats, flag);
  k_moments<true ><<<g1, 256, 0, stream>>>(feats, nump, coors, flag, part, g1);
  k_moments<false><<<g1, 256, 0, stream>>>(feats, nump, coors, flag, part, g1);
  k_reduce<<<68, 256, 0, stream>>>(part, mom, g1);
  k_finalize<true ><<<1, 64, 0, stream>>>(mom, w1, w2, w3, w4, gamma, beta, flag,
                                          wsS, wsT, wsB0hi, wsB0lo, wsB1hi, wsB1lo);
  k_finalize<false><<<1, 64, 0, stream>>>(mom, w1, w2, w3, w4, gamma, beta, flag,
                                          wsS, wsT, wsB0hi, wsB0lo, wsB1hi, wsB1lo);
  k_main<true ><<<N_P / 8, 256, 0, stream>>>(feats, nump, coors, flag, wsS, wsT,
                                             wsB0hi, wsB0lo, wsB1hi, wsB1lo, d_out);
  k_main<false><<<N_P / 8, 256, 0, stream>>>(feats, nump, coors, flag, wsS, wsT,
                                             wsB0hi, wsB0lo, wsB1hi, wsB1lo, d_out);
}